// Round 16
// baseline (666.320 us; speedup 1.0000x reference)
//
#include <hip/hip_runtime.h>
#include <hip/hip_bf16.h>

#define NHEAD 4
#define DIN 128
#define DOUT 128

typedef __attribute__((ext_vector_type(8))) short bf16x8;
typedef __attribute__((ext_vector_type(4))) float f32x4;

__device__ __forceinline__ short bfb(float f) {
    __hip_bfloat16 h = __float2bfloat16(f);
    return *reinterpret_cast<short*>(&h);
}
__device__ __forceinline__ float2 bfpair(unsigned int u) {
    float2 r;
    r.x = __uint_as_float(u << 16);
    r.y = __uint_as_float(u & 0xFFFF0000u);
    return r;
}
__device__ __forceinline__ unsigned int pk2(float lo, float hi) {
    return (unsigned int)(unsigned short)bfb(lo) |
           ((unsigned int)(unsigned short)bfb(hi) << 16);
}
__device__ __forceinline__ bf16x8 cvt8r(float4 a, float4 b) {
    bf16x8 r;
    r[0] = bfb(a.x); r[1] = bfb(a.y); r[2] = bfb(a.z); r[3] = bfb(a.w);
    r[4] = bfb(b.x); r[5] = bfb(b.y); r[6] = bfb(b.z); r[7] = bfb(b.w);
    return r;
}

// ---------------- KP: W->bf16 + CSR rowptr + degree histogram ----------------
__global__ __launch_bounds__(256) void kprep(
    const float* __restrict__ W0, const float* __restrict__ W1,
    const int* __restrict__ erow, uint4* __restrict__ Wbf,
    int* __restrict__ rowptr, int* __restrict__ hist, int n, int E)
{
    const int i = blockIdx.x * 256 + threadIdx.x;
    const int nW8 = (2 * DOUT * DIN) / 8;     // 4096
    if (i < nW8) {
        const float* s = (i < nW8 / 2) ? (W0 + (size_t)i * 8)
                                       : (W1 + (size_t)(i - nW8 / 2) * 8);
        float4 a = ((const float4*)s)[0];
        float4 b = ((const float4*)s)[1];
        Wbf[i] = make_uint4(pk2(a.x, a.y), pk2(a.z, a.w),
                            pk2(b.x, b.y), pk2(b.z, b.w));
        return;
    }
    int nn = i - nW8;
    if (nn > n) return;
    int lo = 0, hi = E;
    while (lo < hi) { int mid = (lo + hi) >> 1; if (erow[mid] < nn) lo = mid + 1; else hi = mid; }
    rowptr[nn] = lo;
    if (nn < n) {
        int lo2 = lo, hi2 = E;
        while (lo2 < hi2) { int mid = (lo2 + hi2) >> 1; if (erow[mid] < nn + 1) lo2 = mid + 1; else hi2 = mid; }
        int deg = lo2 - lo; if (deg > 63) deg = 63;
        atomicAdd(&hist[deg], 1);
    }
}

// ---------------- KS: exclusive prefix of 64-bin histogram ----------------
__global__ void kscan(const int* __restrict__ hist, int* __restrict__ binpos)
{
    if (threadIdx.x == 0 && blockIdx.x == 0) {
        int run = 0;
        for (int b = 0; b < 64; b++) { binpos[b] = run; run += hist[b]; }
    }
}

// ---------------- KC: scatter nodes into degree-sorted order ----------------
__global__ __launch_bounds__(256) void kscatter(
    const int* __restrict__ rowptr, int* __restrict__ binpos,
    int* __restrict__ perm, int n)
{
    int i = blockIdx.x * 256 + threadIdx.x;
    if (i >= n) return;
    int deg = rowptr[i + 1] - rowptr[i]; if (deg > 63) deg = 63;
    int pos = atomicAdd(&binpos[deg], 1);
    perm[pos] = i;
}

// ---------------- K1 tile compute (4 tiles from one LDS half) ----------------
__device__ __forceinline__ void k1_tiles(
    const uint4* __restrict__ ldsbuf, int nodebase, int n,
    int col, int rg, bool selfhalf, int hd,
    const bf16x8 (&afr)[2][4],
    const float4 (&bias4)[2], const float4 (&att4)[2],
    const float4 (&sc4)[2], const float4 (&of4)[2],
    unsigned short* __restrict__ nsbuf, unsigned char* __restrict__ hq,
    float* __restrict__ att_self, unsigned int* __restrict__ ascl)
{
    for (int tt = 0; tt < 4; tt++) {
        const int nl = tt * 16 + col;
        bf16x8 bfr[4];
        #pragma unroll
        for (int kk = 0; kk < 4; kk++) {
            uint4 u = ldsbuf[nl * 16 + ((kk * 4 + rg) ^ (col & 7))];
            *(uint4*)&bfr[kk] = u;
        }

        f32x4 acc[2] = {{0.f,0.f,0.f,0.f},{0.f,0.f,0.f,0.f}};
        #pragma unroll
        for (int kk = 0; kk < 4; kk++) {
            acc[0] = __builtin_amdgcn_mfma_f32_16x16x32_bf16(afr[0][kk], bfr[kk], acc[0], 0, 0, 0);
            acc[1] = __builtin_amdgcn_mfma_f32_16x16x32_bf16(afr[1][kk], bfr[kk], acc[1], 0, 0, 0);
        }

        const int node = nodebase + tt * 16 + col;
        const bool valid = node < n;

        float v[2][4];
        float p = 0.f;
        #pragma unroll
        for (int ct = 0; ct < 2; ct++) {
            v[ct][0] = fmaxf(acc[ct][0] + bias4[ct].x, 0.f);
            v[ct][1] = fmaxf(acc[ct][1] + bias4[ct].y, 0.f);
            v[ct][2] = fmaxf(acc[ct][2] + bias4[ct].z, 0.f);
            v[ct][3] = fmaxf(acc[ct][3] + bias4[ct].w, 0.f);
            p += v[ct][0] * att4[ct].x + v[ct][1] * att4[ct].y
               + v[ct][2] * att4[ct].z + v[ct][3] * att4[ct].w;
        }
        p += __shfl_xor(p, 16);
        p += __shfl_xor(p, 32);

        if (selfhalf) {
            float s = v[0][0]+v[0][1]+v[0][2]+v[0][3]+v[1][0]+v[1][1]+v[1][2]+v[1][3];
            s += __shfl_xor(s, 16);
            s += __shfl_xor(s, 32);
            float m = s * (1.f / 32.f);
            float q = 0.f;
            #pragma unroll
            for (int ct = 0; ct < 2; ct++)
                #pragma unroll
                for (int j = 0; j < 4; j++) { float d = v[ct][j] - m; q += d * d; }
            q += __shfl_xor(q, 16);
            q += __shfl_xor(q, 32);
            float r = rsqrtf(q * (1.f / 32.f) + 1e-9f);
            #pragma unroll
            for (int ct = 0; ct < 2; ct++) {
                float n0 = 0.5f * ((v[ct][0] - m) * sc4[ct].x * r + of4[ct].x);
                float n1 = 0.5f * ((v[ct][1] - m) * sc4[ct].y * r + of4[ct].y);
                float n2 = 0.5f * ((v[ct][2] - m) * sc4[ct].z * r + of4[ct].z);
                float n3 = 0.5f * ((v[ct][3] - m) * sc4[ct].w * r + of4[ct].w);
                ushort4 st;
                st.x = (unsigned short)bfb(n0); st.y = (unsigned short)bfb(n1);
                st.z = (unsigned short)bfb(n2); st.w = (unsigned short)bfb(n3);
                if (valid)
                    *(ushort4*)(nsbuf + (size_t)node * DOUT + hd * 32 + ct * 16 + rg * 4) = st;
            }
            if (rg == 0 && valid)
                att_self[(size_t)node * NHEAD + hd] = p > 0.f ? p : 0.2f * p;
        } else {
            float mh = 0.f;
            #pragma unroll
            for (int ct = 0; ct < 2; ct++)
                #pragma unroll
                for (int j = 0; j < 4; j++) mh = fmaxf(mh, v[ct][j]);
            mh = fmaxf(mh, __shfl_xor(mh, 16));
            mh = fmaxf(mh, __shfl_xor(mh, 32));
            const float rsc = mh > 0.f ? 255.f / mh : 0.f;
            #pragma unroll
            for (int ct = 0; ct < 2; ct++) {
                unsigned int u = 0;
                u |= (unsigned int)(v[ct][0] * rsc + 0.5f);
                u |= (unsigned int)(v[ct][1] * rsc + 0.5f) << 8;
                u |= (unsigned int)(v[ct][2] * rsc + 0.5f) << 16;
                u |= (unsigned int)(v[ct][3] * rsc + 0.5f) << 24;
                if (valid)
                    *(unsigned int*)(hq + (size_t)node * DOUT + hd * 32 + ct * 16 + rg * 4) = u;
            }
            if (rg == 0 && valid) {
                float lg = p > 0.f ? p : 0.2f * p;
                ascl[(size_t)node * NHEAD + hd] = pk2(lg, mh * (1.f / 255.f));
            }
        }
    }
}

// ---------------- K1: double-buffered staging + MFMA dual projection ----------------
#define NPB 128

__global__ __launch_bounds__(512) void k1_mfma(
    const float* __restrict__ feat,
    const uint4* __restrict__ Wbf,
    const float* __restrict__ b0, const float* __restrict__ b1,
    const float* __restrict__ att, const float* __restrict__ scale,
    const float* __restrict__ offset,
    unsigned short* __restrict__ nsbuf, unsigned char* __restrict__ hq,
    float* __restrict__ att_self, unsigned int* __restrict__ ascl, int n)
{
    __shared__ uint4 lds[2][64 * 16];      // 2 x 16 KB
    const int t = threadIdx.x;
    const int w = t >> 6;
    const int lane = t & 63;
    const int col = lane & 15;
    const int rg = lane >> 4;
    const bool selfhalf = (w < 4);
    const int hd = w & 3;

    bf16x8 afr[2][4];
    #pragma unroll
    for (int ct = 0; ct < 2; ct++) {
        const uint4* wr = Wbf + (size_t)(w * 32 + ct * 16 + col) * 16;
        #pragma unroll
        for (int kk = 0; kk < 4; kk++) {
            uint4 u = wr[kk * 4 + rg];
            *(uint4*)&afr[ct][kk] = u;
        }
    }
    float4 bias4[2], att4[2], sc4[2], of4[2];
    #pragma unroll
    for (int ct = 0; ct < 2; ct++) {
        int chg = w * 32 + ct * 16 + rg * 4;
        int chm = chg & 127;
        bias4[ct] = *(const float4*)((selfhalf ? b0 : b1) + chm);
        att4[ct]  = *(const float4*)(att + chg);
        sc4[ct]   = *(const float4*)(scale + 128 + chm);
        of4[ct]   = *(const float4*)(offset + 128 + chm);
    }

    const int base = blockIdx.x * NPB;

    float4 ra[2][2];
    #pragma unroll
    for (int j = 0; j < 2; j++) {
        int li = j * 512 + t;
        int nl = li >> 4, sl = li & 15;
        int ng = base + nl; if (ng >= n) ng = n - 1;
        const float* p = feat + (size_t)ng * DIN + (sl ^ (nl & 7)) * 8;
        ra[j][0] = *(const float4*)p;
        ra[j][1] = *(const float4*)(p + 4);
    }
    #pragma unroll
    for (int j = 0; j < 2; j++) {
        bf16x8 v = cvt8r(ra[j][0], ra[j][1]);
        lds[0][j * 512 + t] = *(uint4*)&v;
    }

    float4 rb[2][2];
    #pragma unroll
    for (int j = 0; j < 2; j++) {
        int li = j * 512 + t;
        int nl = li >> 4, sl = li & 15;
        int ng = base + 64 + nl; if (ng >= n) ng = n - 1;
        const float* p = feat + (size_t)ng * DIN + (sl ^ (nl & 7)) * 8;
        rb[j][0] = *(const float4*)p;
        rb[j][1] = *(const float4*)(p + 4);
    }

    __syncthreads();

    k1_tiles(lds[0], base, n, col, rg, selfhalf, hd, afr, bias4, att4, sc4, of4,
             nsbuf, hq, att_self, ascl);

    #pragma unroll
    for (int j = 0; j < 2; j++) {
        bf16x8 v = cvt8r(rb[j][0], rb[j][1]);
        lds[1][j * 512 + t] = *(uint4*)&v;
    }
    __syncthreads();

    k1_tiles(lds[1], base + 64, n, col, rg, selfhalf, hd, afr, bias4, att4, sc4, of4,
             nsbuf, hq, att_self, ascl);
}

// ---------------- K3: softmax + uint8 weighted aggregate + agg LN + combine ---------
// 256 threads = 32 node-slots/block, 8 lanes/node, 16 channels/thread (uint4 gather).
// Nodes taken in DEGREE-SORTED order via perm[] -> the 8 streams per wave have
// matching trip counts (no convoy loss). Batch-4 2-deep pipeline.
__global__ __launch_bounds__(256) void k3_agg(
    const int* __restrict__ rowptr, const int* __restrict__ ecol,
    const float* __restrict__ eval, const int* __restrict__ perm,
    const float* __restrict__ att_self, const unsigned int* __restrict__ ascl,
    const unsigned short* __restrict__ nsbuf, const unsigned char* __restrict__ hq,
    const float* __restrict__ scale, const float* __restrict__ offset,
    float* __restrict__ out, int n_nodes)
{
    const int t = threadIdx.x;
    const int g = t >> 3;                       // node slot 0..31
    const int lane = t & 7;
    const int nid0 = blockIdx.x * 32 + g;
    if (nid0 >= n_nodes) return;
    const int nid = perm[nid0];
    const int head = lane >> 1;                 // 2 lanes per head
    const int c16 = lane * 16;

    const int start = rowptr[nid], end = rowptr[nid + 1];
    const float as = att_self[(size_t)nid * NHEAD + head];

    float acc[16];
    #pragma unroll
    for (int j = 0; j < 16; j++) acc[j] = 0.f;
    float sumw = 0.f;

    float evA[4];
    unsigned int asA[4];
    uint4 hqA[4];
    int cB[4];
    {
        int cA[4];
        #pragma unroll
        for (int i = 0; i < 4; i++) cA[i] = (start + i     < end) ? ecol[start + i]     : 0;
        #pragma unroll
        for (int i = 0; i < 4; i++) cB[i] = (start + 4 + i < end) ? ecol[start + 4 + i] : 0;
        #pragma unroll
        for (int i = 0; i < 4; i++) {
            evA[i] = (start + i < end) ? eval[start + i] : 0.f;
            asA[i] = ascl[(size_t)cA[i] * NHEAD + head];
            hqA[i] = *(const uint4*)(hq + (size_t)cA[i] * DOUT + c16);
        }
    }

    for (int e = start; e < end; e += 4) {
        float evB[4];
        unsigned int asB[4];
        uint4 hqB[4];
        #pragma unroll
        for (int i = 0; i < 4; i++) {
            evB[i] = (e + 4 + i < end) ? eval[e + 4 + i] : 0.f;
            asB[i] = ascl[(size_t)cB[i] * NHEAD + head];
            hqB[i] = *(const uint4*)(hq + (size_t)cB[i] * DOUT + c16);
        }
        int cC[4];
        #pragma unroll
        for (int i = 0; i < 4; i++)
            cC[i] = (e + 8 + i < end) ? ecol[e + 8 + i] : 0;

        #pragma unroll
        for (int i = 0; i < 4; i++) {
            float2 q = bfpair(asA[i]);               // {att logit, dequant scale}
            float wh = __expf(as + q.x) * evA[i];
            sumw += wh;
            float wq = wh * q.y;
            unsigned int ww[4] = {hqA[i].x, hqA[i].y, hqA[i].z, hqA[i].w};
            #pragma unroll
            for (int k = 0; k < 4; k++) {
                unsigned int hx = ww[k];
                acc[k*4+0] = fmaf(wq, (float)(hx & 255u),         acc[k*4+0]);
                acc[k*4+1] = fmaf(wq, (float)((hx >> 8) & 255u),  acc[k*4+1]);
                acc[k*4+2] = fmaf(wq, (float)((hx >> 16) & 255u), acc[k*4+2]);
                acc[k*4+3] = fmaf(wq, (float)(hx >> 24),          acc[k*4+3]);
            }
        }
        #pragma unroll
        for (int i = 0; i < 4; i++) {
            evA[i] = evB[i]; asA[i] = asB[i]; hqA[i] = hqB[i];
            cB[i] = cC[i];
        }
    }

    const float rden = 1.f / fmaxf(sumw, 1e-10f);
    float a[16];
    #pragma unroll
    for (int j = 0; j < 16; j++) a[j] = acc[j] * rden;

    // layernorm over the head's 32 channels (2 lanes x 16)
    float s0 = 0.f;
    #pragma unroll
    for (int j = 0; j < 16; j++) s0 += a[j];
    s0 += __shfl_xor(s0, 1);
    const float m0 = s0 * (1.f / 32.f);
    float q0 = 0.f;
    #pragma unroll
    for (int j = 0; j < 16; j++) { float d = a[j] - m0; q0 += d * d; }
    q0 += __shfl_xor(q0, 1);
    const float r0 = rsqrtf(q0 * (1.f / 32.f) + 1e-9f);

    #pragma unroll
    for (int c = 0; c < 2; c++) {
        const int cb = c16 + c * 8;
        float4 sca = *(const float4*)(scale + cb);
        float4 scb = *(const float4*)(scale + cb + 4);
        float4 ofa = *(const float4*)(offset + cb);
        float4 ofb = *(const float4*)(offset + cb + 4);
        uint4 nv = *(const uint4*)(nsbuf + (size_t)nid * DOUT + cb);
        float2 p0 = bfpair(nv.x), p1 = bfpair(nv.y), p2 = bfpair(nv.z), p3 = bfpair(nv.w);
        const float* ac = a + c * 8;
        float4 oa, ob;
        oa.x = 0.5f * ((ac[0] - m0) * sca.x * r0 + ofa.x) + p0.x;
        oa.y = 0.5f * ((ac[1] - m0) * sca.y * r0 + ofa.y) + p0.y;
        oa.z = 0.5f * ((ac[2] - m0) * sca.z * r0 + ofa.z) + p1.x;
        oa.w = 0.5f * ((ac[3] - m0) * sca.w * r0 + ofa.w) + p1.y;
        ob.x = 0.5f * ((ac[4] - m0) * scb.x * r0 + ofb.x) + p2.x;
        ob.y = 0.5f * ((ac[5] - m0) * scb.y * r0 + ofb.y) + p2.y;
        ob.z = 0.5f * ((ac[6] - m0) * scb.z * r0 + ofb.z) + p3.x;
        ob.w = 0.5f * ((ac[7] - m0) * scb.w * r0 + ofb.w) + p3.y;
        *(float4*)(out + (size_t)nid * DOUT + cb)     = oa;
        *(float4*)(out + (size_t)nid * DOUT + cb + 4) = ob;
    }
}

extern "C" void kernel_launch(void* const* d_in, const int* in_sizes, int n_in,
                              void* d_out, int out_size, void* d_ws, size_t ws_size,
                              hipStream_t stream) {
    const float* feat  = (const float*)d_in[0];
    const int*   erow  = (const int*)  d_in[1];
    const int*   ecol  = (const int*)  d_in[2];
    const float* eval  = (const float*)d_in[3];
    const float* W0    = (const float*)d_in[4];
    const float* b0    = (const float*)d_in[5];
    const float* W1    = (const float*)d_in[6];
    const float* b1    = (const float*)d_in[7];
    const float* att   = (const float*)d_in[8];
    const float* scale = (const float*)d_in[9];
    const float* offs  = (const float*)d_in[10];
    const int n = in_sizes[0] / DIN;
    const int E = in_sizes[2];

    unsigned short* nsbuf = (unsigned short*)d_ws;                       // n*128 bf16
    unsigned char*  hq    = (unsigned char*)(nsbuf + (size_t)n * DOUT);  // n*128 u8
    unsigned short* Wbf   = (unsigned short*)(hq + (size_t)n * DOUT);    // 32768 bf16
    unsigned int*   ascl  = (unsigned int*)(Wbf + 2 * DOUT * DIN);       // n*4 packed
    float* att_self = (float*)(ascl + (size_t)n * NHEAD);                // n*4
    int*   rowptr   = (int*)(att_self + (size_t)n * NHEAD);              // n+1
    int*   perm     = rowptr + (n + 1);                                  // n
    int*   hist     = perm + n;                                          // 64
    int*   binpos   = hist + 64;                                         // 64

    const int nW8 = (2 * DOUT * DIN) / 8;

    hipMemsetAsync(hist, 0, 64 * sizeof(int), stream);
    kprep<<<(nW8 + n + 1 + 255) / 256, 256, 0, stream>>>(
        W0, W1, erow, (uint4*)Wbf, rowptr, hist, n, E);
    kscan<<<1, 64, 0, stream>>>(hist, binpos);
    kscatter<<<(n + 255) / 256, 256, 0, stream>>>(rowptr, binpos, perm, n);
    k1_mfma<<<(n + NPB - 1) / NPB, 512, 0, stream>>>(
        feat, (const uint4*)Wbf, b0, b1, att, scale, offs,
        nsbuf, hq, att_self, ascl, n);
    k3_agg<<<(n + 31) / 32, 256, 0, stream>>>(rowptr, ecol, eval, perm,
                                              att_self, ascl, nsbuf, hq,
                                              scale, offs, (float*)d_out, n);
}

// Round 17
// 131.099 us; speedup vs baseline: 5.0826x; 5.0826x over previous
//
#include <hip/hip_runtime.h>
#include <hip/hip_bf16.h>

#define NHEAD 4
#define DIN 128
#define DOUT 128

typedef __attribute__((ext_vector_type(8))) short bf16x8;
typedef __attribute__((ext_vector_type(4))) float f32x4;

__device__ __forceinline__ short bfb(float f) {
    __hip_bfloat16 h = __float2bfloat16(f);
    return *reinterpret_cast<short*>(&h);
}
__device__ __forceinline__ float2 bfpair(unsigned int u) {
    float2 r;
    r.x = __uint_as_float(u << 16);
    r.y = __uint_as_float(u & 0xFFFF0000u);
    return r;
}
__device__ __forceinline__ unsigned int pk2(float lo, float hi) {
    return (unsigned int)(unsigned short)bfb(lo) |
           ((unsigned int)(unsigned short)bfb(hi) << 16);
}
__device__ __forceinline__ bf16x8 cvt8r(float4 a, float4 b) {
    bf16x8 r;
    r[0] = bfb(a.x); r[1] = bfb(a.y); r[2] = bfb(a.z); r[3] = bfb(a.w);
    r[4] = bfb(b.x); r[5] = bfb(b.y); r[6] = bfb(b.z); r[7] = bfb(b.w);
    return r;
}

// ---------------- KP: W->bf16 (blocks 0..15) | rowptr + LDS-staged degree hist ------
__global__ __launch_bounds__(256) void kprep(
    const float* __restrict__ W0, const float* __restrict__ W1,
    const int* __restrict__ erow, uint4* __restrict__ Wbf,
    int* __restrict__ rowptr, int* __restrict__ hist, int n, int E)
{
    const int t = threadIdx.x;
    const int nW8 = (2 * DOUT * DIN) / 8;     // 4096 = 16 blocks of 256
    if (blockIdx.x < 16) {
        int i = blockIdx.x * 256 + t;
        const float* s = (i < nW8 / 2) ? (W0 + (size_t)i * 8)
                                       : (W1 + (size_t)(i - nW8 / 2) * 8);
        float4 a = ((const float4*)s)[0];
        float4 b = ((const float4*)s)[1];
        Wbf[i] = make_uint4(pk2(a.x, a.y), pk2(a.z, a.w),
                            pk2(b.x, b.y), pk2(b.z, b.w));
        return;
    }
    __shared__ int lhist[64];
    if (t < 64) lhist[t] = 0;
    __syncthreads();

    int nn = (blockIdx.x - 16) * 256 + t;
    if (nn <= n) {
        int lo = 0, hi = E;
        while (lo < hi) { int mid = (lo + hi) >> 1; if (erow[mid] < nn) lo = mid + 1; else hi = mid; }
        rowptr[nn] = lo;
        if (nn < n) {
            int lo2 = lo, hi2 = E;
            while (lo2 < hi2) { int mid = (lo2 + hi2) >> 1; if (erow[mid] < nn + 1) lo2 = mid + 1; else hi2 = mid; }
            int deg = lo2 - lo; if (deg > 63) deg = 63;
            atomicAdd(&lhist[deg], 1);            // LDS atomic: CU-local
        }
    }
    __syncthreads();
    if (t < 64 && lhist[t] > 0) atomicAdd(&hist[t], lhist[t]);   // <=64 globals/block
}

// ---------------- KS: exclusive prefix of 64-bin histogram ----------------
__global__ void kscan(const int* __restrict__ hist, int* __restrict__ binpos)
{
    if (threadIdx.x == 0 && blockIdx.x == 0) {
        int run = 0;
        for (int b = 0; b < 64; b++) { binpos[b] = run; run += hist[b]; }
    }
}

// ---------------- KC: scatter into degree-sorted order (block-range reservation) ----
__global__ __launch_bounds__(256) void kscatter(
    const int* __restrict__ rowptr, int* __restrict__ binpos,
    int* __restrict__ perm, int n)
{
    __shared__ int lcount[64], lbase[64];
    const int t = threadIdx.x;
    if (t < 64) lcount[t] = 0;
    __syncthreads();

    int i = blockIdx.x * 256 + t;
    int deg = -1, lpos = 0;
    if (i < n) {
        deg = rowptr[i + 1] - rowptr[i]; if (deg > 63) deg = 63;
        lpos = atomicAdd(&lcount[deg], 1);        // LDS atomic
    }
    __syncthreads();
    if (t < 64 && lcount[t] > 0)
        lbase[t] = atomicAdd(&binpos[t], lcount[t]);   // one global per bin per block
    __syncthreads();
    if (i < n)
        perm[lbase[deg] + lpos] = i;
}

// ---------------- K1 tile compute (4 tiles from one LDS half) ----------------
__device__ __forceinline__ void k1_tiles(
    const uint4* __restrict__ ldsbuf, int nodebase, int n,
    int col, int rg, bool selfhalf, int hd,
    const bf16x8 (&afr)[2][4],
    const float4 (&bias4)[2], const float4 (&att4)[2],
    const float4 (&sc4)[2], const float4 (&of4)[2],
    unsigned short* __restrict__ nsbuf, unsigned char* __restrict__ hq,
    float* __restrict__ att_self, unsigned int* __restrict__ ascl)
{
    for (int tt = 0; tt < 4; tt++) {
        const int nl = tt * 16 + col;
        bf16x8 bfr[4];
        #pragma unroll
        for (int kk = 0; kk < 4; kk++) {
            uint4 u = ldsbuf[nl * 16 + ((kk * 4 + rg) ^ (col & 7))];
            *(uint4*)&bfr[kk] = u;
        }

        f32x4 acc[2] = {{0.f,0.f,0.f,0.f},{0.f,0.f,0.f,0.f}};
        #pragma unroll
        for (int kk = 0; kk < 4; kk++) {
            acc[0] = __builtin_amdgcn_mfma_f32_16x16x32_bf16(afr[0][kk], bfr[kk], acc[0], 0, 0, 0);
            acc[1] = __builtin_amdgcn_mfma_f32_16x16x32_bf16(afr[1][kk], bfr[kk], acc[1], 0, 0, 0);
        }

        const int node = nodebase + tt * 16 + col;
        const bool valid = node < n;

        float v[2][4];
        float p = 0.f;
        #pragma unroll
        for (int ct = 0; ct < 2; ct++) {
            v[ct][0] = fmaxf(acc[ct][0] + bias4[ct].x, 0.f);
            v[ct][1] = fmaxf(acc[ct][1] + bias4[ct].y, 0.f);
            v[ct][2] = fmaxf(acc[ct][2] + bias4[ct].z, 0.f);
            v[ct][3] = fmaxf(acc[ct][3] + bias4[ct].w, 0.f);
            p += v[ct][0] * att4[ct].x + v[ct][1] * att4[ct].y
               + v[ct][2] * att4[ct].z + v[ct][3] * att4[ct].w;
        }
        p += __shfl_xor(p, 16);
        p += __shfl_xor(p, 32);

        if (selfhalf) {
            float s = v[0][0]+v[0][1]+v[0][2]+v[0][3]+v[1][0]+v[1][1]+v[1][2]+v[1][3];
            s += __shfl_xor(s, 16);
            s += __shfl_xor(s, 32);
            float m = s * (1.f / 32.f);
            float q = 0.f;
            #pragma unroll
            for (int ct = 0; ct < 2; ct++)
                #pragma unroll
                for (int j = 0; j < 4; j++) { float d = v[ct][j] - m; q += d * d; }
            q += __shfl_xor(q, 16);
            q += __shfl_xor(q, 32);
            float r = rsqrtf(q * (1.f / 32.f) + 1e-9f);
            #pragma unroll
            for (int ct = 0; ct < 2; ct++) {
                float n0 = 0.5f * ((v[ct][0] - m) * sc4[ct].x * r + of4[ct].x);
                float n1 = 0.5f * ((v[ct][1] - m) * sc4[ct].y * r + of4[ct].y);
                float n2 = 0.5f * ((v[ct][2] - m) * sc4[ct].z * r + of4[ct].z);
                float n3 = 0.5f * ((v[ct][3] - m) * sc4[ct].w * r + of4[ct].w);
                ushort4 st;
                st.x = (unsigned short)bfb(n0); st.y = (unsigned short)bfb(n1);
                st.z = (unsigned short)bfb(n2); st.w = (unsigned short)bfb(n3);
                if (valid)
                    *(ushort4*)(nsbuf + (size_t)node * DOUT + hd * 32 + ct * 16 + rg * 4) = st;
            }
            if (rg == 0 && valid)
                att_self[(size_t)node * NHEAD + hd] = p > 0.f ? p : 0.2f * p;
        } else {
            float mh = 0.f;
            #pragma unroll
            for (int ct = 0; ct < 2; ct++)
                #pragma unroll
                for (int j = 0; j < 4; j++) mh = fmaxf(mh, v[ct][j]);
            mh = fmaxf(mh, __shfl_xor(mh, 16));
            mh = fmaxf(mh, __shfl_xor(mh, 32));
            const float rsc = mh > 0.f ? 255.f / mh : 0.f;
            #pragma unroll
            for (int ct = 0; ct < 2; ct++) {
                unsigned int u = 0;
                u |= (unsigned int)(v[ct][0] * rsc + 0.5f);
                u |= (unsigned int)(v[ct][1] * rsc + 0.5f) << 8;
                u |= (unsigned int)(v[ct][2] * rsc + 0.5f) << 16;
                u |= (unsigned int)(v[ct][3] * rsc + 0.5f) << 24;
                if (valid)
                    *(unsigned int*)(hq + (size_t)node * DOUT + hd * 32 + ct * 16 + rg * 4) = u;
            }
            if (rg == 0 && valid) {
                float lg = p > 0.f ? p : 0.2f * p;
                ascl[(size_t)node * NHEAD + hd] = pk2(lg, mh * (1.f / 255.f));
            }
        }
    }
}

// ---------------- K1: double-buffered staging + MFMA dual projection ----------------
#define NPB 128

__global__ __launch_bounds__(512) void k1_mfma(
    const float* __restrict__ feat,
    const uint4* __restrict__ Wbf,
    const float* __restrict__ b0, const float* __restrict__ b1,
    const float* __restrict__ att, const float* __restrict__ scale,
    const float* __restrict__ offset,
    unsigned short* __restrict__ nsbuf, unsigned char* __restrict__ hq,
    float* __restrict__ att_self, unsigned int* __restrict__ ascl, int n)
{
    __shared__ uint4 lds[2][64 * 16];      // 2 x 16 KB
    const int t = threadIdx.x;
    const int w = t >> 6;
    const int lane = t & 63;
    const int col = lane & 15;
    const int rg = lane >> 4;
    const bool selfhalf = (w < 4);
    const int hd = w & 3;

    bf16x8 afr[2][4];
    #pragma unroll
    for (int ct = 0; ct < 2; ct++) {
        const uint4* wr = Wbf + (size_t)(w * 32 + ct * 16 + col) * 16;
        #pragma unroll
        for (int kk = 0; kk < 4; kk++) {
            uint4 u = wr[kk * 4 + rg];
            *(uint4*)&afr[ct][kk] = u;
        }
    }
    float4 bias4[2], att4[2], sc4[2], of4[2];
    #pragma unroll
    for (int ct = 0; ct < 2; ct++) {
        int chg = w * 32 + ct * 16 + rg * 4;
        int chm = chg & 127;
        bias4[ct] = *(const float4*)((selfhalf ? b0 : b1) + chm);
        att4[ct]  = *(const float4*)(att + chg);
        sc4[ct]   = *(const float4*)(scale + 128 + chm);
        of4[ct]   = *(const float4*)(offset + 128 + chm);
    }

    const int base = blockIdx.x * NPB;

    float4 ra[2][2];
    #pragma unroll
    for (int j = 0; j < 2; j++) {
        int li = j * 512 + t;
        int nl = li >> 4, sl = li & 15;
        int ng = base + nl; if (ng >= n) ng = n - 1;
        const float* p = feat + (size_t)ng * DIN + (sl ^ (nl & 7)) * 8;
        ra[j][0] = *(const float4*)p;
        ra[j][1] = *(const float4*)(p + 4);
    }
    #pragma unroll
    for (int j = 0; j < 2; j++) {
        bf16x8 v = cvt8r(ra[j][0], ra[j][1]);
        lds[0][j * 512 + t] = *(uint4*)&v;
    }

    float4 rb[2][2];
    #pragma unroll
    for (int j = 0; j < 2; j++) {
        int li = j * 512 + t;
        int nl = li >> 4, sl = li & 15;
        int ng = base + 64 + nl; if (ng >= n) ng = n - 1;
        const float* p = feat + (size_t)ng * DIN + (sl ^ (nl & 7)) * 8;
        rb[j][0] = *(const float4*)p;
        rb[j][1] = *(const float4*)(p + 4);
    }

    __syncthreads();

    k1_tiles(lds[0], base, n, col, rg, selfhalf, hd, afr, bias4, att4, sc4, of4,
             nsbuf, hq, att_self, ascl);

    #pragma unroll
    for (int j = 0; j < 2; j++) {
        bf16x8 v = cvt8r(rb[j][0], rb[j][1]);
        lds[1][j * 512 + t] = *(uint4*)&v;
    }
    __syncthreads();

    k1_tiles(lds[1], base + 64, n, col, rg, selfhalf, hd, afr, bias4, att4, sc4, of4,
             nsbuf, hq, att_self, ascl);
}

// ---------------- K3: softmax + uint8 weighted aggregate + agg LN + combine ---------
// 256 threads = 32 node-slots/block, 8 lanes/node, 16 channels/thread (uint4 gather).
// Nodes in DEGREE-SORTED order via perm[] -> matched trip counts per wave.
__global__ __launch_bounds__(256) void k3_agg(
    const int* __restrict__ rowptr, const int* __restrict__ ecol,
    const float* __restrict__ eval, const int* __restrict__ perm,
    const float* __restrict__ att_self, const unsigned int* __restrict__ ascl,
    const unsigned short* __restrict__ nsbuf, const unsigned char* __restrict__ hq,
    const float* __restrict__ scale, const float* __restrict__ offset,
    float* __restrict__ out, int n_nodes)
{
    const int t = threadIdx.x;
    const int g = t >> 3;                       // node slot 0..31
    const int lane = t & 7;
    const int nid0 = blockIdx.x * 32 + g;
    if (nid0 >= n_nodes) return;
    const int nid = perm[nid0];
    const int head = lane >> 1;                 // 2 lanes per head
    const int c16 = lane * 16;

    const int start = rowptr[nid], end = rowptr[nid + 1];
    const float as = att_self[(size_t)nid * NHEAD + head];

    float acc[16];
    #pragma unroll
    for (int j = 0; j < 16; j++) acc[j] = 0.f;
    float sumw = 0.f;

    float evA[4];
    unsigned int asA[4];
    uint4 hqA[4];
    int cB[4];
    {
        int cA[4];
        #pragma unroll
        for (int i = 0; i < 4; i++) cA[i] = (start + i     < end) ? ecol[start + i]     : 0;
        #pragma unroll
        for (int i = 0; i < 4; i++) cB[i] = (start + 4 + i < end) ? ecol[start + 4 + i] : 0;
        #pragma unroll
        for (int i = 0; i < 4; i++) {
            evA[i] = (start + i < end) ? eval[start + i] : 0.f;
            asA[i] = ascl[(size_t)cA[i] * NHEAD + head];
            hqA[i] = *(const uint4*)(hq + (size_t)cA[i] * DOUT + c16);
        }
    }

    for (int e = start; e < end; e += 4) {
        float evB[4];
        unsigned int asB[4];
        uint4 hqB[4];
        #pragma unroll
        for (int i = 0; i < 4; i++) {
            evB[i] = (e + 4 + i < end) ? eval[e + 4 + i] : 0.f;
            asB[i] = ascl[(size_t)cB[i] * NHEAD + head];
            hqB[i] = *(const uint4*)(hq + (size_t)cB[i] * DOUT + c16);
        }
        int cC[4];
        #pragma unroll
        for (int i = 0; i < 4; i++)
            cC[i] = (e + 8 + i < end) ? ecol[e + 8 + i] : 0;

        #pragma unroll
        for (int i = 0; i < 4; i++) {
            float2 q = bfpair(asA[i]);               // {att logit, dequant scale}
            float wh = __expf(as + q.x) * evA[i];
            sumw += wh;
            float wq = wh * q.y;
            unsigned int ww[4] = {hqA[i].x, hqA[i].y, hqA[i].z, hqA[i].w};
            #pragma unroll
            for (int k = 0; k < 4; k++) {
                unsigned int hx = ww[k];
                acc[k*4+0] = fmaf(wq, (float)(hx & 255u),         acc[k*4+0]);
                acc[k*4+1] = fmaf(wq, (float)((hx >> 8) & 255u),  acc[k*4+1]);
                acc[k*4+2] = fmaf(wq, (float)((hx >> 16) & 255u), acc[k*4+2]);
                acc[k*4+3] = fmaf(wq, (float)(hx >> 24),          acc[k*4+3]);
            }
        }
        #pragma unroll
        for (int i = 0; i < 4; i++) {
            evA[i] = evB[i]; asA[i] = asB[i]; hqA[i] = hqB[i];
            cB[i] = cC[i];
        }
    }

    const float rden = 1.f / fmaxf(sumw, 1e-10f);
    float a[16];
    #pragma unroll
    for (int j = 0; j < 16; j++) a[j] = acc[j] * rden;

    // layernorm over the head's 32 channels (2 lanes x 16)
    float s0 = 0.f;
    #pragma unroll
    for (int j = 0; j < 16; j++) s0 += a[j];
    s0 += __shfl_xor(s0, 1);
    const float m0 = s0 * (1.f / 32.f);
    float q0 = 0.f;
    #pragma unroll
    for (int j = 0; j < 16; j++) { float d = a[j] - m0; q0 += d * d; }
    q0 += __shfl_xor(q0, 1);
    const float r0 = rsqrtf(q0 * (1.f / 32.f) + 1e-9f);

    #pragma unroll
    for (int c = 0; c < 2; c++) {
        const int cb = c16 + c * 8;
        float4 sca = *(const float4*)(scale + cb);
        float4 scb = *(const float4*)(scale + cb + 4);
        float4 ofa = *(const float4*)(offset + cb);
        float4 ofb = *(const float4*)(offset + cb + 4);
        uint4 nv = *(const uint4*)(nsbuf + (size_t)nid * DOUT + cb);
        float2 p0 = bfpair(nv.x), p1 = bfpair(nv.y), p2 = bfpair(nv.z), p3 = bfpair(nv.w);
        const float* ac = a + c * 8;
        float4 oa, ob;
        oa.x = 0.5f * ((ac[0] - m0) * sca.x * r0 + ofa.x) + p0.x;
        oa.y = 0.5f * ((ac[1] - m0) * sca.y * r0 + ofa.y) + p0.y;
        oa.z = 0.5f * ((ac[2] - m0) * sca.z * r0 + ofa.z) + p1.x;
        oa.w = 0.5f * ((ac[3] - m0) * sca.w * r0 + ofa.w) + p1.y;
        ob.x = 0.5f * ((ac[4] - m0) * scb.x * r0 + ofb.x) + p2.x;
        ob.y = 0.5f * ((ac[5] - m0) * scb.y * r0 + ofb.y) + p2.y;
        ob.z = 0.5f * ((ac[6] - m0) * scb.z * r0 + ofb.z) + p3.x;
        ob.w = 0.5f * ((ac[7] - m0) * scb.w * r0 + ofb.w) + p3.y;
        *(float4*)(out + (size_t)nid * DOUT + cb)     = oa;
        *(float4*)(out + (size_t)nid * DOUT + cb + 4) = ob;
    }
}

extern "C" void kernel_launch(void* const* d_in, const int* in_sizes, int n_in,
                              void* d_out, int out_size, void* d_ws, size_t ws_size,
                              hipStream_t stream) {
    const float* feat  = (const float*)d_in[0];
    const int*   erow  = (const int*)  d_in[1];
    const int*   ecol  = (const int*)  d_in[2];
    const float* eval  = (const float*)d_in[3];
    const float* W0    = (const float*)d_in[4];
    const float* b0    = (const float*)d_in[5];
    const float* W1    = (const float*)d_in[6];
    const float* b1    = (const float*)d_in[7];
    const float* att   = (const float*)d_in[8];
    const float* scale = (const float*)d_in[9];
    const float* offs  = (const float*)d_in[10];
    const int n = in_sizes[0] / DIN;
    const int E = in_sizes[2];

    unsigned short* nsbuf = (unsigned short*)d_ws;                       // n*128 bf16
    unsigned char*  hq    = (unsigned char*)(nsbuf + (size_t)n * DOUT);  // n*128 u8
    unsigned short* Wbf   = (unsigned short*)(hq + (size_t)n * DOUT);    // 32768 bf16
    unsigned int*   ascl  = (unsigned int*)(Wbf + 2 * DOUT * DIN);       // n*4 packed
    float* att_self = (float*)(ascl + (size_t)n * NHEAD);                // n*4
    int*   rowptr   = (int*)(att_self + (size_t)n * NHEAD);              // n+1
    int*   perm     = rowptr + (n + 1);                                  // n
    int*   hist     = perm + n;                                          // 64
    int*   binpos   = hist + 64;                                         // 64

    hipMemsetAsync(hist, 0, 64 * sizeof(int), stream);
    kprep<<<16 + (n + 1 + 255) / 256, 256, 0, stream>>>(
        W0, W1, erow, (uint4*)Wbf, rowptr, hist, n, E);
    kscan<<<1, 64, 0, stream>>>(hist, binpos);
    kscatter<<<(n + 255) / 256, 256, 0, stream>>>(rowptr, binpos, perm, n);
    k1_mfma<<<(n + NPB - 1) / NPB, 512, 0, stream>>>(
        feat, (const uint4*)Wbf, b0, b1, att, scale, offs,
        nsbuf, hq, att_self, ascl, n);
    k3_agg<<<(n + 31) / 32, 256, 0, stream>>>(rowptr, ecol, eval, perm,
                                              att_self, ascl, nsbuf, hq,
                                              scale, offs, (float*)d_out, n);
}

// Round 18
// 96.086 us; speedup vs baseline: 6.9346x; 1.3644x over previous
//
#include <hip/hip_runtime.h>
#include <hip/hip_bf16.h>

#define NHEAD 4
#define DIN 128
#define DOUT 128

typedef __attribute__((ext_vector_type(8))) short bf16x8;
typedef __attribute__((ext_vector_type(4))) float f32x4;

__device__ __forceinline__ short bfb(float f) {
    __hip_bfloat16 h = __float2bfloat16(f);
    return *reinterpret_cast<short*>(&h);
}
__device__ __forceinline__ float2 bfpair(unsigned int u) {
    float2 r;
    r.x = __uint_as_float(u << 16);
    r.y = __uint_as_float(u & 0xFFFF0000u);
    return r;
}
__device__ __forceinline__ unsigned int pk2(float lo, float hi) {
    return (unsigned int)(unsigned short)bfb(lo) |
           ((unsigned int)(unsigned short)bfb(hi) << 16);
}
__device__ __forceinline__ bf16x8 cvt8r(float4 a, float4 b) {
    bf16x8 r;
    r[0] = bfb(a.x); r[1] = bfb(a.y); r[2] = bfb(a.z); r[3] = bfb(a.w);
    r[4] = bfb(b.x); r[5] = bfb(b.y); r[6] = bfb(b.z); r[7] = bfb(b.w);
    return r;
}

// ---------------- KP: W -> bf16 (tiny) ----------------
__global__ __launch_bounds__(256) void kprep_w(
    const float* __restrict__ W0, const float* __restrict__ W1,
    uint4* __restrict__ Wbf)
{
    const int i = blockIdx.x * 256 + threadIdx.x;
    const int nW8 = (2 * DOUT * DIN) / 8;     // 4096
    if (i >= nW8) return;
    const float* s = (i < nW8 / 2) ? (W0 + (size_t)i * 8)
                                   : (W1 + (size_t)(i - nW8 / 2) * 8);
    float4 a = ((const float4*)s)[0];
    float4 b = ((const float4*)s)[1];
    Wbf[i] = make_uint4(pk2(a.x, a.y), pk2(a.z, a.w),
                        pk2(b.x, b.y), pk2(b.z, b.w));
}

// ---------------- K1 tile compute (4 tiles from one LDS half) ----------------
__device__ __forceinline__ void k1_tiles(
    const uint4* __restrict__ ldsbuf, int nodebase, int n,
    int col, int rg, bool selfhalf, int hd,
    const bf16x8 (&afr)[2][4],
    const float4 (&bias4)[2], const float4 (&att4)[2],
    const float4 (&sc4)[2], const float4 (&of4)[2],
    unsigned short* __restrict__ nsbuf, unsigned char* __restrict__ hq,
    float* __restrict__ att_self, unsigned int* __restrict__ ascl)
{
    for (int tt = 0; tt < 4; tt++) {
        const int nl = tt * 16 + col;
        bf16x8 bfr[4];
        #pragma unroll
        for (int kk = 0; kk < 4; kk++) {
            uint4 u = ldsbuf[nl * 16 + ((kk * 4 + rg) ^ (col & 7))];
            *(uint4*)&bfr[kk] = u;
        }

        f32x4 acc[2] = {{0.f,0.f,0.f,0.f},{0.f,0.f,0.f,0.f}};
        #pragma unroll
        for (int kk = 0; kk < 4; kk++) {
            acc[0] = __builtin_amdgcn_mfma_f32_16x16x32_bf16(afr[0][kk], bfr[kk], acc[0], 0, 0, 0);
            acc[1] = __builtin_amdgcn_mfma_f32_16x16x32_bf16(afr[1][kk], bfr[kk], acc[1], 0, 0, 0);
        }

        const int node = nodebase + tt * 16 + col;
        const bool valid = node < n;

        float v[2][4];
        float p = 0.f;
        #pragma unroll
        for (int ct = 0; ct < 2; ct++) {
            v[ct][0] = fmaxf(acc[ct][0] + bias4[ct].x, 0.f);
            v[ct][1] = fmaxf(acc[ct][1] + bias4[ct].y, 0.f);
            v[ct][2] = fmaxf(acc[ct][2] + bias4[ct].z, 0.f);
            v[ct][3] = fmaxf(acc[ct][3] + bias4[ct].w, 0.f);
            p += v[ct][0] * att4[ct].x + v[ct][1] * att4[ct].y
               + v[ct][2] * att4[ct].z + v[ct][3] * att4[ct].w;
        }
        p += __shfl_xor(p, 16);
        p += __shfl_xor(p, 32);

        if (selfhalf) {
            float s = v[0][0]+v[0][1]+v[0][2]+v[0][3]+v[1][0]+v[1][1]+v[1][2]+v[1][3];
            s += __shfl_xor(s, 16);
            s += __shfl_xor(s, 32);
            float m = s * (1.f / 32.f);
            float q = 0.f;
            #pragma unroll
            for (int ct = 0; ct < 2; ct++)
                #pragma unroll
                for (int j = 0; j < 4; j++) { float d = v[ct][j] - m; q += d * d; }
            q += __shfl_xor(q, 16);
            q += __shfl_xor(q, 32);
            float r = rsqrtf(q * (1.f / 32.f) + 1e-9f);
            #pragma unroll
            for (int ct = 0; ct < 2; ct++) {
                float n0 = 0.5f * ((v[ct][0] - m) * sc4[ct].x * r + of4[ct].x);
                float n1 = 0.5f * ((v[ct][1] - m) * sc4[ct].y * r + of4[ct].y);
                float n2 = 0.5f * ((v[ct][2] - m) * sc4[ct].z * r + of4[ct].z);
                float n3 = 0.5f * ((v[ct][3] - m) * sc4[ct].w * r + of4[ct].w);
                ushort4 st;
                st.x = (unsigned short)bfb(n0); st.y = (unsigned short)bfb(n1);
                st.z = (unsigned short)bfb(n2); st.w = (unsigned short)bfb(n3);
                if (valid)
                    *(ushort4*)(nsbuf + (size_t)node * DOUT + hd * 32 + ct * 16 + rg * 4) = st;
            }
            if (rg == 0 && valid)
                att_self[(size_t)node * NHEAD + hd] = p > 0.f ? p : 0.2f * p;
        } else {
            float mh = 0.f;
            #pragma unroll
            for (int ct = 0; ct < 2; ct++)
                #pragma unroll
                for (int j = 0; j < 4; j++) mh = fmaxf(mh, v[ct][j]);
            mh = fmaxf(mh, __shfl_xor(mh, 16));
            mh = fmaxf(mh, __shfl_xor(mh, 32));
            const float rsc = mh > 0.f ? 255.f / mh : 0.f;
            #pragma unroll
            for (int ct = 0; ct < 2; ct++) {
                unsigned int u = 0;
                u |= (unsigned int)(v[ct][0] * rsc + 0.5f);
                u |= (unsigned int)(v[ct][1] * rsc + 0.5f) << 8;
                u |= (unsigned int)(v[ct][2] * rsc + 0.5f) << 16;
                u |= (unsigned int)(v[ct][3] * rsc + 0.5f) << 24;
                if (valid)
                    *(unsigned int*)(hq + (size_t)node * DOUT + hd * 32 + ct * 16 + rg * 4) = u;
            }
            if (rg == 0 && valid) {
                float lg = p > 0.f ? p : 0.2f * p;
                ascl[(size_t)node * NHEAD + hd] = pk2(lg, mh * (1.f / 255.f));
            }
        }
    }
}

// ---------------- K1: double-buffered staging + MFMA + fused rowptr tail ------------
#define NPB 128

__global__ __launch_bounds__(512) void k1_mfma(
    const float* __restrict__ feat,
    const uint4* __restrict__ Wbf,
    const float* __restrict__ b0, const float* __restrict__ b1,
    const float* __restrict__ att, const float* __restrict__ scale,
    const float* __restrict__ offset,
    unsigned short* __restrict__ nsbuf, unsigned char* __restrict__ hq,
    float* __restrict__ att_self, unsigned int* __restrict__ ascl,
    const int* __restrict__ erow, int* __restrict__ rowptr,
    int n, int E, int NB1)
{
    __shared__ uint4 lds[2][64 * 16];      // 2 x 16 KB
    const int t = threadIdx.x;

    if ((int)blockIdx.x >= NB1) {
        int idx = ((int)blockIdx.x - NB1) * 512 + t;
        if (idx <= n) {
            int lo = 0, hi = E;
            while (lo < hi) { int mid = (lo + hi) >> 1; if (erow[mid] < idx) lo = mid + 1; else hi = mid; }
            rowptr[idx] = lo;
        }
        return;
    }

    const int w = t >> 6;
    const int lane = t & 63;
    const int col = lane & 15;
    const int rg = lane >> 4;
    const bool selfhalf = (w < 4);
    const int hd = w & 3;

    bf16x8 afr[2][4];
    #pragma unroll
    for (int ct = 0; ct < 2; ct++) {
        const uint4* wr = Wbf + (size_t)(w * 32 + ct * 16 + col) * 16;
        #pragma unroll
        for (int kk = 0; kk < 4; kk++) {
            uint4 u = wr[kk * 4 + rg];
            *(uint4*)&afr[ct][kk] = u;
        }
    }
    float4 bias4[2], att4[2], sc4[2], of4[2];
    #pragma unroll
    for (int ct = 0; ct < 2; ct++) {
        int chg = w * 32 + ct * 16 + rg * 4;
        int chm = chg & 127;
        bias4[ct] = *(const float4*)((selfhalf ? b0 : b1) + chm);
        att4[ct]  = *(const float4*)(att + chg);
        sc4[ct]   = *(const float4*)(scale + 128 + chm);
        of4[ct]   = *(const float4*)(offset + 128 + chm);
    }

    const int base = blockIdx.x * NPB;

    float4 ra[2][2];
    #pragma unroll
    for (int j = 0; j < 2; j++) {
        int li = j * 512 + t;
        int nl = li >> 4, sl = li & 15;
        int ng = base + nl; if (ng >= n) ng = n - 1;
        const float* p = feat + (size_t)ng * DIN + (sl ^ (nl & 7)) * 8;
        ra[j][0] = *(const float4*)p;
        ra[j][1] = *(const float4*)(p + 4);
    }
    #pragma unroll
    for (int j = 0; j < 2; j++) {
        bf16x8 v = cvt8r(ra[j][0], ra[j][1]);
        lds[0][j * 512 + t] = *(uint4*)&v;
    }

    float4 rb[2][2];
    #pragma unroll
    for (int j = 0; j < 2; j++) {
        int li = j * 512 + t;
        int nl = li >> 4, sl = li & 15;
        int ng = base + 64 + nl; if (ng >= n) ng = n - 1;
        const float* p = feat + (size_t)ng * DIN + (sl ^ (nl & 7)) * 8;
        rb[j][0] = *(const float4*)p;
        rb[j][1] = *(const float4*)(p + 4);
    }

    __syncthreads();

    k1_tiles(lds[0], base, n, col, rg, selfhalf, hd, afr, bias4, att4, sc4, of4,
             nsbuf, hq, att_self, ascl);

    #pragma unroll
    for (int j = 0; j < 2; j++) {
        bf16x8 v = cvt8r(rb[j][0], rb[j][1]);
        lds[1][j * 512 + t] = *(uint4*)&v;
    }
    __syncthreads();

    k1_tiles(lds[1], base + 64, n, col, rg, selfhalf, hd, afr, bias4, att4, sc4, of4,
             nsbuf, hq, att_self, ascl);
}

// ---------------- K3: softmax + uint8 weighted aggregate + agg LN + combine ---------
// 256 threads = 32 nodes/block, 8 lanes/node, 16 channels/thread (uint4 gather).
// 8 independent edge streams per wave. Batch-4 2-deep pipeline.
__global__ __launch_bounds__(256) void k3_agg(
    const int* __restrict__ rowptr, const int* __restrict__ ecol,
    const float* __restrict__ eval,
    const float* __restrict__ att_self, const unsigned int* __restrict__ ascl,
    const unsigned short* __restrict__ nsbuf, const unsigned char* __restrict__ hq,
    const float* __restrict__ scale, const float* __restrict__ offset,
    float* __restrict__ out, int n_nodes)
{
    const int t = threadIdx.x;
    const int g = t >> 3;                       // node slot 0..31
    const int lane = t & 7;
    const int nid = blockIdx.x * 32 + g;
    if (nid >= n_nodes) return;
    const int head = lane >> 1;                 // 2 lanes per head
    const int c16 = lane * 16;

    const int start = rowptr[nid], end = rowptr[nid + 1];
    const float as = att_self[(size_t)nid * NHEAD + head];

    float acc[16];
    #pragma unroll
    for (int j = 0; j < 16; j++) acc[j] = 0.f;
    float sumw = 0.f;

    float evA[4];
    unsigned int asA[4];
    uint4 hqA[4];
    int cB[4];
    {
        int cA[4];
        #pragma unroll
        for (int i = 0; i < 4; i++) cA[i] = (start + i     < end) ? ecol[start + i]     : 0;
        #pragma unroll
        for (int i = 0; i < 4; i++) cB[i] = (start + 4 + i < end) ? ecol[start + 4 + i] : 0;
        #pragma unroll
        for (int i = 0; i < 4; i++) {
            evA[i] = (start + i < end) ? eval[start + i] : 0.f;
            asA[i] = ascl[(size_t)cA[i] * NHEAD + head];
            hqA[i] = *(const uint4*)(hq + (size_t)cA[i] * DOUT + c16);
        }
    }

    for (int e = start; e < end; e += 4) {
        float evB[4];
        unsigned int asB[4];
        uint4 hqB[4];
        #pragma unroll
        for (int i = 0; i < 4; i++) {
            evB[i] = (e + 4 + i < end) ? eval[e + 4 + i] : 0.f;
            asB[i] = ascl[(size_t)cB[i] * NHEAD + head];
            hqB[i] = *(const uint4*)(hq + (size_t)cB[i] * DOUT + c16);
        }
        int cC[4];
        #pragma unroll
        for (int i = 0; i < 4; i++)
            cC[i] = (e + 8 + i < end) ? ecol[e + 8 + i] : 0;

        #pragma unroll
        for (int i = 0; i < 4; i++) {
            float2 q = bfpair(asA[i]);               // {att logit, dequant scale}
            float wh = __expf(as + q.x) * evA[i];
            sumw += wh;
            float wq = wh * q.y;
            unsigned int ww[4] = {hqA[i].x, hqA[i].y, hqA[i].z, hqA[i].w};
            #pragma unroll
            for (int k = 0; k < 4; k++) {
                unsigned int hx = ww[k];
                acc[k*4+0] = fmaf(wq, (float)(hx & 255u),         acc[k*4+0]);
                acc[k*4+1] = fmaf(wq, (float)((hx >> 8) & 255u),  acc[k*4+1]);
                acc[k*4+2] = fmaf(wq, (float)((hx >> 16) & 255u), acc[k*4+2]);
                acc[k*4+3] = fmaf(wq, (float)(hx >> 24),          acc[k*4+3]);
            }
        }
        #pragma unroll
        for (int i = 0; i < 4; i++) {
            evA[i] = evB[i]; asA[i] = asB[i]; hqA[i] = hqB[i];
            cB[i] = cC[i];
        }
    }

    const float rden = 1.f / fmaxf(sumw, 1e-10f);
    float a[16];
    #pragma unroll
    for (int j = 0; j < 16; j++) a[j] = acc[j] * rden;

    // layernorm over the head's 32 channels (2 lanes x 16)
    float s0 = 0.f;
    #pragma unroll
    for (int j = 0; j < 16; j++) s0 += a[j];
    s0 += __shfl_xor(s0, 1);
    const float m0 = s0 * (1.f / 32.f);
    float q0 = 0.f;
    #pragma unroll
    for (int j = 0; j < 16; j++) { float d = a[j] - m0; q0 += d * d; }
    q0 += __shfl_xor(q0, 1);
    const float r0 = rsqrtf(q0 * (1.f / 32.f) + 1e-9f);

    #pragma unroll
    for (int c = 0; c < 2; c++) {
        const int cb = c16 + c * 8;
        float4 sca = *(const float4*)(scale + cb);
        float4 scb = *(const float4*)(scale + cb + 4);
        float4 ofa = *(const float4*)(offset + cb);
        float4 ofb = *(const float4*)(offset + cb + 4);
        uint4 nv = *(const uint4*)(nsbuf + (size_t)nid * DOUT + cb);
        float2 p0 = bfpair(nv.x), p1 = bfpair(nv.y), p2 = bfpair(nv.z), p3 = bfpair(nv.w);
        const float* ac = a + c * 8;
        float4 oa, ob;
        oa.x = 0.5f * ((ac[0] - m0) * sca.x * r0 + ofa.x) + p0.x;
        oa.y = 0.5f * ((ac[1] - m0) * sca.y * r0 + ofa.y) + p0.y;
        oa.z = 0.5f * ((ac[2] - m0) * sca.z * r0 + ofa.z) + p1.x;
        oa.w = 0.5f * ((ac[3] - m0) * sca.w * r0 + ofa.w) + p1.y;
        ob.x = 0.5f * ((ac[4] - m0) * scb.x * r0 + ofb.x) + p2.x;
        ob.y = 0.5f * ((ac[5] - m0) * scb.y * r0 + ofb.y) + p2.y;
        ob.z = 0.5f * ((ac[6] - m0) * scb.z * r0 + ofb.z) + p3.x;
        ob.w = 0.5f * ((ac[7] - m0) * scb.w * r0 + ofb.w) + p3.y;
        *(float4*)(out + (size_t)nid * DOUT + cb)     = oa;
        *(float4*)(out + (size_t)nid * DOUT + cb + 4) = ob;
    }
}

extern "C" void kernel_launch(void* const* d_in, const int* in_sizes, int n_in,
                              void* d_out, int out_size, void* d_ws, size_t ws_size,
                              hipStream_t stream) {
    const float* feat  = (const float*)d_in[0];
    const int*   erow  = (const int*)  d_in[1];
    const int*   ecol  = (const int*)  d_in[2];
    const float* eval  = (const float*)d_in[3];
    const float* W0    = (const float*)d_in[4];
    const float* b0    = (const float*)d_in[5];
    const float* W1    = (const float*)d_in[6];
    const float* b1    = (const float*)d_in[7];
    const float* att   = (const float*)d_in[8];
    const float* scale = (const float*)d_in[9];
    const float* offs  = (const float*)d_in[10];
    const int n = in_sizes[0] / DIN;
    const int E = in_sizes[2];

    unsigned short* nsbuf = (unsigned short*)d_ws;                       // n*128 bf16
    unsigned char*  hq    = (unsigned char*)(nsbuf + (size_t)n * DOUT);  // n*128 u8
    unsigned short* Wbf   = (unsigned short*)(hq + (size_t)n * DOUT);    // 32768 bf16
    unsigned int*   ascl  = (unsigned int*)(Wbf + 2 * DOUT * DIN);       // n*4 packed
    float* att_self = (float*)(ascl + (size_t)n * NHEAD);                // n*4
    int*   rowptr   = (int*)(att_self + (size_t)n * NHEAD);              // n+1

    const int NB1 = (n + NPB - 1) / NPB;
    const int NBr = (n + 512) / 512;

    kprep_w<<<16, 256, 0, stream>>>(W0, W1, (uint4*)Wbf);
    k1_mfma<<<NB1 + NBr, 512, 0, stream>>>(
        feat, (const uint4*)Wbf, b0, b1, att, scale, offs,
        nsbuf, hq, att_self, ascl, erow, rowptr, n, E, NB1);
    k3_agg<<<(n + 31) / 32, 256, 0, stream>>>(rowptr, ecol, eval, att_self, ascl,
                                              nsbuf, hq, scale, offs,
                                              (float*)d_out, n);
}